// Round 12
// baseline (939.882 us; speedup 1.0000x reference)
//
#include <hip/hip_runtime.h>
#include <hip/hip_bf16.h>
#include <math.h>

#define B_   16
#define L_   2048
#define D_   128
#define H_   4
#define NL_  4
#define DK_  32
#define DFF_ 256
#define INTD_ 11
#define F_OUT 129
#define DM_  16
#define FMINV (-3.402823466e38f)
#define LOG2E 1.4426950408889634f

#define BL_  (B_*L_)      // 32768
#define SZ_X (BL_*D_)     // 4194304 floats

#define PSTR 72           // attn P-scratch stride

#define WT_Q 0
#define WT_K 16384
#define WT_V 32768
#define WT_O 49152
#define WT_1 65536
#define WT_2 98304
#define WT_TOT 131072

typedef __attribute__((ext_vector_type(8))) short bf16x8;
typedef __attribute__((ext_vector_type(4))) float f32x4;

#if __has_builtin(__builtin_amdgcn_exp2f)
#define EXP2F(x) __builtin_amdgcn_exp2f(x)
#else
#define EXP2F(x) __expf(0.69314718055994531f*(x))
#endif

static __device__ __forceinline__ short f2bf(float x) {
    union { __hip_bfloat16 h; short s; } u;
    u.h = __float2bfloat16(x);
    return u.s;
}
static __device__ __forceinline__ float bf2f(short s) {
    union { __hip_bfloat16 h; short t; } u;
    u.t = s;
    return __bfloat162float(u.h);
}
static __device__ __forceinline__ void split2(float v, short& h, short& l) {
    h = f2bf(v); l = f2bf(v - bf2f(h));
}
static __device__ __forceinline__ void split_trunc(float v, short& h, short& l) {
    unsigned u = __float_as_uint(v);
    h = (short)(u >> 16);
    float r = v - __uint_as_float(u & 0xffff0000u);
    l = (short)(__float_as_uint(r) >> 16);
}

// ---------------------------------------------------------------------------
// Mask compaction: pos[b,l] = compact index or -1; kcount[b]; cfm[b,j]=0/FMIN.
// ---------------------------------------------------------------------------
__global__ __launch_bounds__(256)
void compact_kernel(const int* __restrict__ mask, int* __restrict__ pos,
                    int* __restrict__ kcount, float* __restrict__ cfm)
{
    int b = blockIdx.x, t = threadIdx.x;
    int lane = t & 63, w = t >> 6;
    __shared__ int wsum[4];
    __shared__ int tot_s;
    int mv[8], loc[8], s = 0;
#pragma unroll
    for (int i = 0; i < 8; ++i) {
        mv[i] = mask[b*L_ + t*8 + i];
        loc[i] = s;
        s += mv[i];
    }
    int v = s;
#pragma unroll
    for (int d = 1; d < 64; d <<= 1) {
        int y = __shfl_up(v, d);
        if (lane >= d) v += y;
    }
    int excl = v - s;
    if (lane == 63) wsum[w] = v;
    __syncthreads();
    int wbase = 0;
    for (int i = 0; i < w; ++i) wbase += wsum[i];
    int base = wbase + excl;
#pragma unroll
    for (int i = 0; i < 8; ++i)
        pos[b*L_ + t*8 + i] = mv[i] ? (base + loc[i]) : -1;
    if (t == 255) { kcount[b] = base + s; tot_s = base + s; }
    __syncthreads();
    int tot = tot_s;
    for (int l = t; l < L_; l += 256) cfm[b*L_ + l] = (l < tot) ? 0.0f : FMINV;
}

// ---------------------------------------------------------------------------
// Embedding with compaction
// ---------------------------------------------------------------------------
__global__ __launch_bounds__(128)
void embed_kernel(const float* __restrict__ values, const float* __restrict__ times,
                  const int* __restrict__ variables, const int* __restrict__ pos,
                  const float* __restrict__ W1t, const float* __restrict__ b1t,
                  const float* __restrict__ W2t,
                  const float* __restrict__ W1v, const float* __restrict__ b1v,
                  const float* __restrict__ W2v,
                  const float* __restrict__ var_table, float* __restrict__ x)
{
    int bl = blockIdx.x;
    int p  = pos[bl];
    if (p < 0) return;
    int t  = threadIdx.x;
    __shared__ float th[INTD_], vh[INTD_];
    if (t < INTD_)                th[t]    = tanhf(times[bl]  * W1t[t]    + b1t[t]);
    if (t >= 64 && t < 64+INTD_)  vh[t-64] = tanhf(values[bl] * W1v[t-64] + b1v[t-64]);
    __syncthreads();
    int var = variables[bl];
    float acc = var_table[var*D_ + t];
#pragma unroll
    for (int i = 0; i < INTD_; ++i)
        acc += th[i]*W2t[i*D_ + t] + vh[i]*W2v[i*D_ + t];
    x[((size_t)((bl >> 11)*2048 + p))*D_ + t] = acc;
}

// zero compact x tail rows [Kb, ceil64(Kb)) once
__global__ __launch_bounds__(256)
void xtail_zero_kernel(const int* __restrict__ kcount, float* __restrict__ x)
{
    int b = blockIdx.x, t = threadIdx.x;
    int Kb = kcount[b];
    int end = (Kb + 63) & ~63;
    int tot = (end - Kb) * D_;
    for (int i = t; i < tot; i += 256)
        x[((size_t)(b*2048 + Kb))*D_ + i] = 0.0f;
}

// ---------------------------------------------------------------------------
// Weight pre-splits
// ---------------------------------------------------------------------------
__global__ __launch_bounds__(256)
void split_all_kernel(const float* __restrict__ Wq, const float* __restrict__ Wk,
                      const float* __restrict__ Wv, const float* __restrict__ Wo,
                      const float* __restrict__ W1, const float* __restrict__ W2,
                      short* __restrict__ hi, short* __restrict__ lo)
{
    int gidx = blockIdx.x*256 + threadIdx.x;
    int layer = gidx >> 17;
    int idx   = gidx & 131071;
    float v;
    if (idx < 49152) {
        int which = idx >> 14;
        int r = idx & 16383;
        int col = r >> 7, k = r & 127;
        int h = col >> 5, e = col & 31;
        const float* src = ((which == 0) ? Wq : (which == 1) ? Wk : Wv)
                           + (size_t)layer*H_*D_*DK_;
        v = src[(h*D_ + k)*DK_ + e];
    } else if (idx < 65536) {
        int r = idx - 49152;
        int col = r >> 7, k = r & 127;
        v = Wo[(size_t)layer*D_*D_ + k*D_ + col];
    } else if (idx < 98304) {
        int r = idx - 65536;
        int col = r >> 7, k = r & 127;
        v = W1[(size_t)layer*D_*DFF_ + k*DFF_ + col];
    } else {
        int r = idx - 98304;
        int col = r >> 8, k = r & 255;
        v = W2[(size_t)layer*DFF_*D_ + k*D_ + col];
    }
    short h2, l2; split2(v, h2, l2);
    hi[gidx] = h2; lo[gidx] = l2;
}

__global__ __launch_bounds__(256)
void split_nk_kernel(const float* __restrict__ W, short* __restrict__ hi,
                     short* __restrict__ lo, int N, int K)
{
    int idx = blockIdx.x*256 + threadIdx.x;
    int col = idx / K, k = idx - col*K;
    float v = W[k*N + col];
    short h2, l2; split2(v, h2, l2);
    hi[idx] = h2; lo[idx] = l2;
}

// ---------------------------------------------------------------------------
// MFMA GEMM on COMPACT rows. RB = rows per block (32 or 64).
// EPI: 1=+resid 2=+bias,gelu 3=+bias,+resid 7=fusion att dot (+cfm, RB=64)
// ---------------------------------------------------------------------------
template<int EPI, int RB>
__global__ __launch_bounds__(256)
void gemm_mfma(const float* __restrict__ A, const short* __restrict__ Whi,
               const short* __restrict__ Wlo, const float* __restrict__ bias,
               const float* __restrict__ resid, float* __restrict__ out,
               const float* __restrict__ cfm, const int* __restrict__ kcount,
               int N, int K)
{
    const int row0 = blockIdx.x * RB;
    const int bb = row0 >> 11;
    if ((row0 & 2047) >= ((kcount[bb] + 63) & ~63)) return;

    __shared__ short Ahi[RB*136];
    __shared__ short Alo[RB*136];
    __shared__ float part[64][16];
    const int t = threadIdx.x;
    const int w = t >> 6, lane = t & 63;
    const int m = lane & 15, qd = lane >> 4;
    const int col0 = blockIdx.y * 128;

    f32x4 acc[RB/16][2];
#pragma unroll
    for (int r4 = 0; r4 < RB/16; ++r4)
#pragma unroll
        for (int j = 0; j < 2; ++j) acc[r4][j] = (f32x4){0,0,0,0};

    for (int kb = 0; kb < K; kb += 128) {
        if (kb) __syncthreads();
#pragma unroll
        for (int i = 0; i < RB/8; ++i) {
            int r = (t >> 5) + 8*i;
            int c = (t & 31) * 4;
            float4 av = *(const float4*)(A + (size_t)(row0 + r)*K + kb + c);
            short4 hi4, lo4;
            split2(av.x, hi4.x, lo4.x);
            split2(av.y, hi4.y, lo4.y);
            split2(av.z, hi4.z, lo4.z);
            split2(av.w, hi4.w, lo4.w);
            *(short4*)&Ahi[r*136 + c] = hi4;
            *(short4*)&Alo[r*136 + c] = lo4;
        }
        __syncthreads();

#pragma unroll
        for (int ks = 0; ks < 4; ++ks) {
            bf16x8 wh[2], wl[2];
#pragma unroll
            for (int j = 0; j < 2; ++j) {
                size_t wi = (size_t)(col0 + 32*w + 16*j + m)*K + kb + 32*ks + 8*qd;
                wh[j] = *(const bf16x8*)(Whi + wi);
                wl[j] = *(const bf16x8*)(Wlo + wi);
            }
#pragma unroll
            for (int r4 = 0; r4 < RB/16; ++r4) {
                bf16x8 ah = *(const bf16x8*)&Ahi[(16*r4 + m)*136 + 32*ks + 8*qd];
                bf16x8 al = *(const bf16x8*)&Alo[(16*r4 + m)*136 + 32*ks + 8*qd];
#pragma unroll
                for (int j = 0; j < 2; ++j) {
                    acc[r4][j] = __builtin_amdgcn_mfma_f32_16x16x32_bf16(wh[j], ah, acc[r4][j], 0, 0, 0);
                    acc[r4][j] = __builtin_amdgcn_mfma_f32_16x16x32_bf16(wh[j], al, acc[r4][j], 0, 0, 0);
                    acc[r4][j] = __builtin_amdgcn_mfma_f32_16x16x32_bf16(wl[j], ah, acc[r4][j], 0, 0, 0);
                }
            }
        }
    }

#pragma unroll
    for (int r4 = 0; r4 < RB/16; ++r4) {
        int row = row0 + 16*r4 + m;
        float dotp = 0.0f;
#pragma unroll
        for (int j = 0; j < 2; ++j) {
            int col = col0 + 32*w + 16*j + 4*qd;
            f32x4 v = acc[r4][j];
            if (EPI == 2 || EPI == 3 || EPI == 7) {
                float4 bv = *(const float4*)(bias + col);
                v[0] += bv.x; v[1] += bv.y; v[2] += bv.z; v[3] += bv.w;
            }
            if (EPI == 2) {
#pragma unroll
                for (int e = 0; e < 4; ++e)
                    v[e] = 0.5f * v[e] * (1.0f + erff(v[e] * 0.70710678118654752f));
            }
            if (EPI == 7) {
#pragma unroll
                for (int e = 0; e < 4; ++e) v[e] = tanhf(v[e]);
            }
            if (EPI == 1 || EPI == 3) {
                float4 rv = *(const float4*)(resid + (size_t)row*N + col);
                v[0] += rv.x; v[1] += rv.y; v[2] += rv.z; v[3] += rv.w;
            }
            if (EPI == 7) {
                float4 uv = *(const float4*)(resid + col);   // uf
                dotp += v[0]*uv.x + v[1]*uv.y + v[2]*uv.z + v[3]*uv.w;
            } else {
                float4 sv = {v[0], v[1], v[2], v[3]};
                *(float4*)(out + (size_t)row*N + col) = sv;
            }
        }
        if (EPI == 7) part[16*r4 + m][4*w + qd] = dotp;
    }
    if (EPI == 7) {
        __syncthreads();
        if (t < RB) {
            float s = 0.0f;
#pragma unroll
            for (int i = 0; i < 16; ++i) s += part[t][i];
            out[row0 + t] = s + cfm[row0 + t];
        }
    }
}

// ---------------------------------------------------------------------------
// Fused QKV GEMM on compact rows, RB=32: Q fp32; K hi/lo head-major; V^T hi/lo.
// ---------------------------------------------------------------------------
__global__ __launch_bounds__(256)
void gemm_qkv_fused(const float* __restrict__ A, const short* __restrict__ Whi,
                    const short* __restrict__ Wlo, const int* __restrict__ kcount,
                    float* __restrict__ qout,
                    short* __restrict__ khi, short* __restrict__ klo,
                    short* __restrict__ vhiT, short* __restrict__ vloT)
{
    const int RB = 32;
    const int row0 = blockIdx.x * RB;
    const int bb = row0 >> 11;
    if ((row0 & 2047) >= ((kcount[bb] + 63) & ~63)) return;

    __shared__ short Ahi[RB*136];
    __shared__ short Alo[RB*136];
    const int t = threadIdx.x;
    const int w = t >> 6, lane = t & 63;
    const int m = lane & 15, qd = lane >> 4;

#pragma unroll
    for (int i = 0; i < RB/8; ++i) {
        int r = (t >> 5) + 8*i;
        int c = (t & 31) * 4;
        float4 av = *(const float4*)(A + (size_t)(row0 + r)*D_ + c);
        short4 hi4, lo4;
        split2(av.x, hi4.x, lo4.x);
        split2(av.y, hi4.y, lo4.y);
        split2(av.z, hi4.z, lo4.z);
        split2(av.w, hi4.w, lo4.w);
        *(short4*)&Ahi[r*136 + c] = hi4;
        *(short4*)&Alo[r*136 + c] = lo4;
    }
    __syncthreads();

#pragma unroll
    for (int sec = 0; sec < 3; ++sec) {
        const short* Wh = Whi + sec*16384;
        const short* Wl = Wlo + sec*16384;
        f32x4 acc[RB/16][2];
#pragma unroll
        for (int r4 = 0; r4 < RB/16; ++r4)
#pragma unroll
            for (int j = 0; j < 2; ++j) acc[r4][j] = (f32x4){0,0,0,0};

#pragma unroll
        for (int ks = 0; ks < 4; ++ks) {
            bf16x8 wh[2], wl[2];
#pragma unroll
            for (int j = 0; j < 2; ++j) {
                size_t wi = (size_t)(32*w + 16*j + m)*D_ + 32*ks + 8*qd;
                wh[j] = *(const bf16x8*)(Wh + wi);
                wl[j] = *(const bf16x8*)(Wl + wi);
            }
#pragma unroll
            for (int r4 = 0; r4 < RB/16; ++r4) {
                bf16x8 ah = *(const bf16x8*)&Ahi[(16*r4 + m)*136 + 32*ks + 8*qd];
                bf16x8 al = *(const bf16x8*)&Alo[(16*r4 + m)*136 + 32*ks + 8*qd];
#pragma unroll
                for (int j = 0; j < 2; ++j) {
                    acc[r4][j] = __builtin_amdgcn_mfma_f32_16x16x32_bf16(wh[j], ah, acc[r4][j], 0, 0, 0);
                    acc[r4][j] = __builtin_amdgcn_mfma_f32_16x16x32_bf16(wh[j], al, acc[r4][j], 0, 0, 0);
                    acc[r4][j] = __builtin_amdgcn_mfma_f32_16x16x32_bf16(wl[j], ah, acc[r4][j], 0, 0, 0);
                }
            }
        }

#pragma unroll
        for (int r4 = 0; r4 < RB/16; ++r4) {
            int row = row0 + 16*r4 + m;
            int l = row & 2047;
#pragma unroll
            for (int j = 0; j < 2; ++j) {
                int col = 32*w + 16*j + 4*qd;
                f32x4 v = acc[r4][j];
                if (sec == 0) {
                    float4 sv = {v[0], v[1], v[2], v[3]};
                    *(float4*)(qout + (size_t)row*D_ + col) = sv;
                } else if (sec == 1) {
                    size_t idx = ((size_t)((bb*4 + w)*2048 + l))*32 + (col & 31);
                    short4 hi4, lo4;
                    split2(v[0], hi4.x, lo4.x);
                    split2(v[1], hi4.y, lo4.y);
                    split2(v[2], hi4.z, lo4.z);
                    split2(v[3], hi4.w, lo4.w);
                    *(short4*)(khi + idx) = hi4;
                    *(short4*)(klo + idx) = lo4;
                } else {
                    size_t basep = (size_t)(bb*4 + w)*32;
#pragma unroll
                    for (int e = 0; e < 4; ++e) {
                        int d = 16*j + 4*qd + e;
                        short hh, ll; split2(v[e], hh, ll);
                        vhiT[(basep + d)*2048 + l] = hh;
                        vloT[(basep + d)*2048 + l] = ll;
                    }
                }
            }
        }
    }
}

// ---------------------------------------------------------------------------
// MFMA flash attention over compact rows: 128 queries/block (2 q-sets
// sharing one K/V staging) -> 48 MFMA/wave per barrier instead of 24.
// ---------------------------------------------------------------------------
__global__ __launch_bounds__(256)
void attn_mfma_kernel(const float* __restrict__ q,
                      const short* __restrict__ khi, const short* __restrict__ klo,
                      const short* __restrict__ vhiT, const short* __restrict__ vloT,
                      const int* __restrict__ kcount, const float* __restrict__ cfm,
                      float* __restrict__ o)
{
    __shared__ short KhiS[64*32];
    __shared__ short KloS[64*32];
    __shared__ short Vthi[32*72];
    __shared__ short Vtlo[32*72];
    __shared__ short Pshi[2][4][16*PSTR];
    __shared__ short Pslo[2][4][16*PSTR];
    __shared__ float kmf[64];
    __shared__ float al_ls[2][4][16];
    __shared__ float l_ls [2][4][16];

    const int t    = threadIdx.x;
    const int w    = t >> 6;
    const int lane = t & 63;
    const int m    = lane & 15;
    const int qd   = lane >> 4;
    const int qt2 = blockIdx.x, h = blockIdx.y, b = blockIdx.z;

    const int Kb = kcount[b];
    if (qt2*128 >= Kb) return;
    const int nt = (Kb + 63) >> 6;

    const size_t hd = ((size_t)(b*4 + h))*2048*32;
    const int vd = t >> 3;
    const int vk = (t & 7) * 8;
    const size_t vbase = ((size_t)(b*4 + h)*32 + vd)*2048 + vk;

    // ---- two register-resident Q fragments (sets s=0,1) ----
    bf16x8 qhi[2], qlo[2];
#pragma unroll
    for (int s = 0; s < 2; ++s) {
        const int qrow = qt2*128 + 64*s + 16*w + m;
        const float* qp = q + ((size_t)(b*L_ + qrow))*D_ + h*DK_ + 8*qd;
        float qf[8];
        *(float4*)&qf[0] = *(const float4*)qp;
        *(float4*)&qf[4] = *(const float4*)(qp + 4);
#pragma unroll
        for (int j = 0; j < 8; ++j) {
            float qs = qf[j] * LOG2E;
            short hs = f2bf(qs);
            qhi[s][j] = hs;
            qlo[s][j] = f2bf(qs - bf2f(hs));
        }
    }

    bf16x8 pkh, pkl, pvh, pvl;
    float4 pmask = {0,0,0,0};
    {
        const size_t gk = hd + (size_t)t*8;
        pkh = *(const bf16x8*)(khi + gk);
        pkl = *(const bf16x8*)(klo + gk);
        pvh = *(const bf16x8*)(vhiT + vbase);
        pvl = *(const bf16x8*)(vloT + vbase);
        if (t < 16) pmask = ((const float4*)(cfm + (size_t)b*L_))[t];
    }

    float m_old[2] = {-INFINITY, -INFINITY}, l_run[2] = {0.0f, 0.0f};
    f32x4 o_acc[2][2];
#pragma unroll
    for (int s = 0; s < 2; ++s)
#pragma unroll
        for (int tp = 0; tp < 2; ++tp) o_acc[s][tp] = (f32x4){0,0,0,0};

    for (int kt = 0; kt < nt; ++kt) {
        __syncthreads();
        *(bf16x8*)&KhiS[t*8] = pkh;
        *(bf16x8*)&KloS[t*8] = pkl;
        *(bf16x8*)&Vthi[vd*72 + vk] = pvh;
        *(bf16x8*)&Vtlo[vd*72 + vk] = pvl;
        if (t < 16) ((float4*)kmf)[t] = pmask;
        __syncthreads();
        if (kt + 1 < nt) {
            const size_t gk = hd + (size_t)(kt+1)*64*32 + t*8;
            pkh = *(const bf16x8*)(khi + gk);
            pkl = *(const bf16x8*)(klo + gk);
            pvh = *(const bf16x8*)(vhiT + vbase + (size_t)(kt+1)*64);
            pvl = *(const bf16x8*)(vloT + vbase + (size_t)(kt+1)*64);
            if (t < 16) pmask = ((const float4*)(cfm + (size_t)b*L_ + (size_t)(kt+1)*64))[t];
        }

#pragma unroll
        for (int s = 0; s < 2; ++s) {
            // ---- S^T = K·Q^T (split-precision, fp32 acc, log2 domain) ----
            f32x4 sf[4];
#pragma unroll
            for (int k4 = 0; k4 < 4; ++k4) {
                bf16x8 ka = *(const bf16x8*)&KhiS[(16*k4 + m)*32 + 8*qd];
                bf16x8 kl = *(const bf16x8*)&KloS[(16*k4 + m)*32 + 8*qd];
                f32x4 c = {0,0,0,0};
                c = __builtin_amdgcn_mfma_f32_16x16x32_bf16(ka, qhi[s], c, 0, 0, 0);
                c = __builtin_amdgcn_mfma_f32_16x16x32_bf16(ka, qlo[s], c, 0, 0, 0);
                c = __builtin_amdgcn_mfma_f32_16x16x32_bf16(kl, qhi[s], c, 0, 0, 0);
                sf[k4] = c;
            }

            float sv[16];
#pragma unroll
            for (int k4 = 0; k4 < 4; ++k4) {
                float4 kmv = *(const float4*)&kmf[16*k4 + 4*qd];
                sv[4*k4+0] = sf[k4][0] + kmv.x;
                sv[4*k4+1] = sf[k4][1] + kmv.y;
                sv[4*k4+2] = sf[k4][2] + kmv.z;
                sv[4*k4+3] = sf[k4][3] + kmv.w;
            }

            float tmax = sv[0];
#pragma unroll
            for (int j = 1; j < 16; ++j) tmax = fmaxf(tmax, sv[j]);
            tmax = fmaxf(tmax, __shfl_xor(tmax, 16));
            tmax = fmaxf(tmax, __shfl_xor(tmax, 32));
            float mnew  = fmaxf(m_old[s], tmax);
            float alpha = EXP2F(m_old[s] - mnew);
            float psum = 0.0f;
            short pbh[16], pbl[16];
#pragma unroll
            for (int j = 0; j < 16; ++j) {
                float p = EXP2F(sv[j] - mnew);
                psum += p;
                split_trunc(p, pbh[j], pbl[j]);
            }
            psum += __shfl_xor(psum, 16);
            psum += __shfl_xor(psum, 32);
            l_run[s] = l_run[s] * alpha + psum;
            m_old[s] = mnew;

#pragma unroll
            for (int k4 = 0; k4 < 4; ++k4) {
                short4 s4h, s4l;
                s4h.x = pbh[4*k4+0]; s4h.y = pbh[4*k4+1]; s4h.z = pbh[4*k4+2]; s4h.w = pbh[4*k4+3];
                s4l.x = pbl[4*k4+0]; s4l.y = pbl[4*k4+1]; s4l.z = pbl[4*k4+2]; s4l.w = pbl[4*k4+3];
                *(short4*)&Pshi[s][w][m*PSTR + 16*k4 + 4*qd] = s4h;
                *(short4*)&Pslo[s][w][m*PSTR + 16*k4 + 4*qd] = s4l;
            }
            if (lane < 16) al_ls[s][w][lane] = alpha;

            {
                float4 alr = *(const float4*)&al_ls[s][w][4*qd];
                o_acc[s][0][0]*=alr.x; o_acc[s][0][1]*=alr.y; o_acc[s][0][2]*=alr.z; o_acc[s][0][3]*=alr.w;
                o_acc[s][1][0]*=alr.x; o_acc[s][1][1]*=alr.y; o_acc[s][1][2]*=alr.z; o_acc[s][1][3]*=alr.w;
            }
#pragma unroll
            for (int sg = 0; sg < 2; ++sg) {
                bf16x8 pah = *(const bf16x8*)&Pshi[s][w][m*PSTR + 32*sg + 8*qd];
                bf16x8 pal = *(const bf16x8*)&Pslo[s][w][m*PSTR + 32*sg + 8*qd];
#pragma unroll
                for (int tp = 0; tp < 2; ++tp) {
                    bf16x8 vh = *(const bf16x8*)&Vthi[(16*tp + m)*72 + 32*sg + 8*qd];
                    bf16x8 vl = *(const bf16x8*)&Vtlo[(16*tp + m)*72 + 32*sg + 8*qd];
                    o_acc[s][tp] = __builtin_amdgcn_mfma_f32_16x16x32_bf16(pah, vh, o_acc[s][tp], 0, 0, 0);
                    o_acc[s][tp] = __builtin_amdgcn_mfma_f32_16x16x32_bf16(pah, vl, o_acc[s][tp], 0, 0, 0);
                    o_acc[s][tp] = __builtin_amdgcn_mfma_f32_16x16x32_bf16(pal, vh, o_acc[s][tp], 0, 0, 0);
                }
            }
        }
    }

#pragma unroll
    for (int s = 0; s < 2; ++s) {
        if (lane < 16) l_ls[s][w][lane] = l_run[s];
        float4 lr = *(const float4*)&l_ls[s][w][4*qd];
        float li[4] = {1.0f/lr.x, 1.0f/lr.y, 1.0f/lr.z, 1.0f/lr.w};
#pragma unroll
        for (int tp = 0; tp < 2; ++tp)
#pragma unroll
            for (int r = 0; r < 4; ++r)
                o[((size_t)(b*L_ + qt2*128 + 64*s + 16*w + 4*qd + r))*D_ + h*DK_ + 16*tp + m] =
                    o_acc[s][tp][r] * li[r];
    }
}

// ---------------------------------------------------------------------------
// Pooling
// ---------------------------------------------------------------------------
__global__ __launch_bounds__(256)
void pool_stats_kernel(const float* __restrict__ att, const int* __restrict__ kcount,
                       float* __restrict__ p)
{
    int b = blockIdx.x, t = threadIdx.x;
    int lim = (kcount[b] + 63) & ~63;
    __shared__ float red[4];
    __shared__ float a_s[L_];

    float m = -INFINITY;
    for (int l = t; l < L_; l += 256) {
        float a = (l < lim) ? att[b*L_ + l] : FMINV;
        a_s[l] = a;
        m = fmaxf(m, a);
    }
#pragma unroll
    for (int s = 1; s < 64; s <<= 1) m = fmaxf(m, __shfl_xor(m, s));
    if ((t & 63) == 0) red[t >> 6] = m;
    __syncthreads();
    m = fmaxf(fmaxf(red[0], red[1]), fmaxf(red[2], red[3]));
    __syncthreads();

    float s = 0.0f;
    for (int l = t; l < L_; l += 256) s += __expf(a_s[l] - m);
#pragma unroll
    for (int st = 1; st < 64; st <<= 1) s += __shfl_xor(s, st);
    if ((t & 63) == 0) red[t >> 6] = s;
    __syncthreads();
    s = red[0] + red[1] + red[2] + red[3];
    float inv = 1.0f / s;
    for (int l = t; l < L_; l += 256)
        p[b*L_ + l] = (l < lim) ? __expf(a_s[l] - m) * inv : 0.0f;
}

__global__ __launch_bounds__(128)
void pool_partial_kernel(const float* __restrict__ p, const float* __restrict__ x,
                         float* __restrict__ part)
{
    int c = blockIdx.x, b = blockIdx.y, d = threadIdx.x;
    const float* xb = x + ((size_t)(b*L_ + c*128))*D_ + d;
    const float* pb = p + b*L_ + c*128;
    float acc = 0.0f;
#pragma unroll 4
    for (int i = 0; i < 128; ++i) acc += pb[i] * xb[(size_t)i*D_];
    part[((size_t)b*16 + c)*D_ + d] = acc;
}

// ---------------------------------------------------------------------------
// Demographics MLP
// ---------------------------------------------------------------------------
__global__ __launch_bounds__(256)
void demo_kernel(const float* __restrict__ demog, const float* __restrict__ Wd1,
                 const float* __restrict__ bd1, const float* __restrict__ Wd2,
                 const float* __restrict__ bd2, float* __restrict__ demo_out)
{
    int t = threadIdx.x;
    __shared__ float dsm[B_][DM_];
    __shared__ float hs[B_][2*D_];
    if (t < B_*DM_) dsm[t >> 4][t & 15] = demog[t];
    __syncthreads();
    {
        int col = t;
#pragma unroll
        for (int r = 0; r < B_; ++r) {
            float acc = bd1[col];
#pragma unroll
            for (int kk = 0; kk < DM_; ++kk) acc += dsm[r][kk]*Wd1[kk*(2*D_)+col];
            hs[r][col] = tanhf(acc);
        }
    }
    __syncthreads();
    {
        int c  = t & (D_-1);
        int r0 = t >> 7;
        for (int r = r0; r < B_; r += 2) {
            float acc = bd2[c];
            for (int kk = 0; kk < 2*D_; ++kk) acc += hs[r][kk]*Wd2[kk*D_+c];
            demo_out[r*D_+c] = acc;
        }
    }
}

// ---------------------------------------------------------------------------
// Head
// ---------------------------------------------------------------------------
__global__ __launch_bounds__(256)
void head_kernel(const float* __restrict__ part, const float* __restrict__ demo,
                 const float* __restrict__ Wh, const float* __restrict__ bh,
                 float* __restrict__ out)
{
    int b = blockIdx.x, t = threadIdx.x;
    __shared__ float tss[128];
    if (t < 128) {
        float s = 0.0f;
#pragma unroll
        for (int c = 0; c < 16; ++c) s += part[((size_t)b*16 + c)*D_ + t];
        tss[t] = s;
    }
    __syncthreads();
    if (t >= F_OUT) return;
    float acc = bh[t];
    for (int k2 = 0; k2 < D_; ++k2) acc += tss[k2]         * Wh[k2*F_OUT + t];
    for (int k2 = 0; k2 < D_; ++k2) acc += demo[b*D_ + k2] * Wh[(D_+k2)*F_OUT + t];
    out[b*F_OUT + t] = acc;
}

// ---------------------------------------------------------------------------
extern "C" void kernel_launch(void* const* d_in, const int* in_sizes, int n_in,
                              void* d_out, int out_size, void* d_ws, size_t ws_size,
                              hipStream_t stream)
{
    (void)in_sizes; (void)n_in; (void)out_size; (void)ws_size;
    const float* values       = (const float*)d_in[0];
    const float* times        = (const float*)d_in[1];
    const int*   variables    = (const int*)  d_in[2];
    const int*   input_mask   = (const int*)  d_in[3];
    const float* demographics = (const float*)d_in[4];
    const float* W1t = (const float*)d_in[5];
    const float* b1t = (const float*)d_in[6];
    const float* W2t = (const float*)d_in[7];
    const float* W1v = (const float*)d_in[8];
    const float* b1v = (const float*)d_in[9];
    const float* W2v = (const float*)d_in[10];
    const float* var_table = (const float*)d_in[11];
    const float* Wq  = (const float*)d_in[12];
    const float* Wk  = (const float*)d_in[13];
    const float* Wv  = (const float*)d_in[14];
    const float* Wo  = (const float*)d_in[15];
    const float* W1  = (const float*)d_in[16];
    const float* b1  = (const float*)d_in[17];
    const float* W2  = (const float*)d_in[18];
    const float* b2  = (const float*)d_in[19];
    const float* Wf  = (const float*)d_in[20];
    const float* bfv = (const float*)d_in[21];
    const float* uf  = (const float*)d_in[22];
    const float* Wd1 = (const float*)d_in[23];
    const float* bd1 = (const float*)d_in[24];
    const float* Wd2 = (const float*)d_in[25];
    const float* bd2 = (const float*)d_in[26];
    const float* Wh  = (const float*)d_in[27];
    const float* bhv = (const float*)d_in[28];
    float* out = (float*)d_out;

    float* ws     = (float*)d_ws;
    float* x      = ws;                   // compact rows
    float* qb     = ws + (size_t)SZ_X;
    float* region = ws + (size_t)2*SZ_X;
    short* khi    = (short*)region;
    short* klo    = khi + (size_t)SZ_X;
    short* vhiT   = klo + (size_t)SZ_X;
    short* vloT   = vhiT + (size_t)SZ_X;
    float* hb     = region;               // alias (FFN hidden)
    float* attb   = ws + (size_t)4*SZ_X;  // BL_
    float* attp   = attb + BL_;           // BL_
    float* partb  = attp + BL_;           // B_*16*D_
    float* demob  = partb + B_*16*D_;     // B_*D_
    short* wt_hi  = (short*)(demob + B_*D_);
    short* wt_lo  = wt_hi + (size_t)NL_*WT_TOT;
    short* wfhi   = wt_lo + (size_t)NL_*WT_TOT;
    short* wflo   = wfhi + 16384;
    int*   posb   = (int*)(wflo + 16384);       // BL_
    int*   kcountb= posb + BL_;                 // B_
    float* cfmb   = (float*)(kcountb + B_);     // BL_

    compact_kernel<<<B_, 256, 0, stream>>>(input_mask, posb, kcountb, cfmb);
    embed_kernel<<<BL_, 128, 0, stream>>>(values, times, variables, posb,
                                          W1t, b1t, W2t, W1v, b1v, W2v,
                                          var_table, x);
    xtail_zero_kernel<<<B_, 256, 0, stream>>>(kcountb, x);
    demo_kernel<<<1, 256, 0, stream>>>(demographics, Wd1, bd1, Wd2, bd2, demob);
    split_nk_kernel<<<64, 256, 0, stream>>>(Wf, wfhi, wflo, D_, D_);
    split_all_kernel<<<NL_*512, 256, 0, stream>>>(Wq, Wk, Wv, Wo, W1, W2, wt_hi, wt_lo);

    for (int i = 0; i < NL_; ++i) {
        short* whL = wt_hi + (size_t)i*WT_TOT;
        short* wlL = wt_lo + (size_t)i*WT_TOT;
        gemm_qkv_fused<<<BL_/32, 256, 0, stream>>>(x, whL, wlL, kcountb,
            qb, khi, klo, vhiT, vloT);
        attn_mfma_kernel<<<dim3(L_/128, H_, B_), 256, 0, stream>>>(qb, khi, klo, vhiT, vloT,
                                                                   kcountb, cfmb, qb);
        gemm_mfma<1,32><<<dim3(BL_/32, 1), 256, 0, stream>>>(qb, whL+WT_O, wlL+WT_O,
            nullptr, x, x, nullptr, kcountb, D_, D_);
        gemm_mfma<2,64><<<dim3(BL_/64, 2), 256, 0, stream>>>(x, whL+WT_1, wlL+WT_1,
            b1 + i*DFF_, nullptr, hb, nullptr, kcountb, DFF_, D_);
        gemm_mfma<3,32><<<dim3(BL_/32, 1), 256, 0, stream>>>(hb, whL+WT_2, wlL+WT_2,
            b2 + i*D_, x, x, nullptr, kcountb, D_, DFF_);
    }

    // fused fusion-attention on compact rows: att = tanh(x@Wf+bf).uf + cfm
    gemm_mfma<7,64><<<dim3(BL_/64, 1), 256, 0, stream>>>(x, wfhi, wflo,
        bfv, uf, attb, cfmb, kcountb, D_, D_);
    pool_stats_kernel<<<B_, 256, 0, stream>>>(attb, kcountb, attp);
    pool_partial_kernel<<<dim3(16, B_), 128, 0, stream>>>(attp, x, partb);
    head_kernel<<<B_, 256, 0, stream>>>(partb, demob, Wh, bhv, out);
}